// Round 1
// baseline (170.196 us; speedup 1.0000x reference)
//
#include <hip/hip_runtime.h>
#include <math.h>

// ---------------------------------------------------------------------------
// Exp-domain reformulation of the log-domain tree machine.
// All lsp() log-softmaxes become sigmoids; logsumexp over X_DIM becomes a
// length-16 dot product of probabilities; compare_fwd becomes a 4-step
// multiplicative recurrence; only 2 logf per node + final 256-way
// max-subtracted logsumexp remain transcendental.
// ---------------------------------------------------------------------------

// workspace layout (float offsets)
#define NWS_EY   0        // ey[1020][16]     : exp(y) address distributions
#define NWS_ED   16320    // ed[1020][2]      : (ed0, ed1) = exp(lsp(dw))
#define NWS_XC   20400    // xc[1020][2]      : (X20, X21) = exp(lsp(cw))
#define NWS_EV0  24480    // ev0[8][256]      : transposed [d][k]
#define NWS_EV1  26528    // ev1[8][256]
// total 28576 floats = 114304 B

struct WPtrs {
  const float* sw[8];
  const float* dw[8];
  const float* cw[8];
  const float* vw;
};

__device__ __forceinline__ float sigmoidf(float x) {
  return 1.0f / (1.0f + expf(-x));
}

__global__ void tm_precompute(WPtrs p, float* __restrict__ ws) {
  int tid = blockIdx.x * blockDim.x + threadIdx.x;
  if (tid < 1020) {
    int jg = tid;
    int v = (jg >> 2) + 1;
    int depth = 31 - __clz(v);                 // depth i: jg in [4(2^i-1), 4(2^{i+1}-1))
    int nS = (1 << depth) * 4;                 // rows (n*SHUF) at this depth
    int jl = jg - 4 * ((1 << depth) - 1);      // local j within depth
    const float* sw = p.sw[depth];             // shape (2, nS, 4)
    float p0[4];
#pragma unroll
    for (int k = 0; k < 4; k++)
      p0[k] = sigmoidf(sw[jl * 4 + k] - sw[nS * 4 + jl * 4 + k]);
#pragma unroll
    for (int a = 0; a < 16; a++) {
      float prod = 1.0f;
#pragma unroll
      for (int k = 0; k < 4; k++) {
        int bit = (a >> (3 - k)) & 1;          // ADDR bit order: k=0 is MSB
        prod *= bit ? p0[k] : (1.0f - p0[k]);
      }
      ws[NWS_EY + jg * 16 + a] = prod;
    }
    const float* dw = p.dw[depth];             // shape (2, nS)
    float e0 = sigmoidf(dw[jl] - dw[nS + jl]);
    ws[NWS_ED + jg * 2 + 0] = e0;
    ws[NWS_ED + jg * 2 + 1] = 1.0f - e0;
    const float* cw = p.cw[depth];             // shape (2, 1, n, 4) -> (2, nS)
    float c0 = sigmoidf(cw[jl] - cw[nS + jl]);
    ws[NWS_XC + jg * 2 + 0] = c0;
    ws[NWS_XC + jg * 2 + 1] = 1.0f - c0;
  } else if (tid >= 1024 && tid < 3072) {
    int e = tid - 1024;                        // e = k*8 + d
    int k = e >> 3, d = e & 7;
    float v0 = sigmoidf(p.vw[e] - p.vw[2048 + e]);
    ws[NWS_EV0 + d * 256 + k] = v0;            // transposed [d][k]
    ws[NWS_EV1 + d * 256 + k] = 1.0f - v0;
  }
}

#define BPB 8   // batch elements per block

__global__ __launch_bounds__(256) void tm_main(
    const float* __restrict__ x0, const float* __restrict__ x1,
    const float* __restrict__ ws, float* __restrict__ out) {
  __shared__ float ex0s[BPB][16];
  __shared__ float ex1s[BPB][16];
  __shared__ float a_lds[BPB][255][2];         // per-node (a1, a2) in log domain
  __shared__ float ev0s[2048];                 // [d][k]
  __shared__ float ev1s[2048];

  const int t  = threadIdx.x;
  const int b0 = blockIdx.x * BPB;

  // stage exp(x) for this block's 8 batch rows
  {
    int bl = t >> 5, a = t & 31;
    if (a < 16) ex0s[bl][a]      = expf(x0[(b0 + bl) * 16 + a]);
    else        ex1s[bl][a - 16] = expf(x1[(b0 + bl) * 16 + (a - 16)]);
  }
  // stage value tables
  for (int e = t; e < 2048; e += 256) {
    ev0s[e] = ws[NWS_EV0 + e];
    ev1s[e] = ws[NWS_EV1 + e];
  }
  __syncthreads();

  const int bl    = t >> 5;   // which of the 8 batch rows
  const int chunk = t & 31;   // 32-way node split

  const float*  __restrict__ ey = ws + NWS_EY;
  const float2* __restrict__ ED = (const float2*)(ws + NWS_ED);
  const float2* __restrict__ XC = (const float2*)(ws + NWS_XC);

  // phase 2: per-node compare_fwd recurrence in exp domain
  for (int ng = chunk; ng < 255; ng += 32) {
    int depth = 31 - __clz(ng + 1);
    int tloc  = ng - ((1 << depth) - 1);
    int jbase = 4 * ((1 << depth) - 1) + tloc * 4;
    float S1 = 1.8600378e-44f;                 // exp(-BOUND - lc - LOG2)
    float S2 = 1.0f;                           // exp(BOUND - lc) = exp(0)
    float S3 = 1.8600378e-44f;
#pragma unroll
    for (int s = 0; s < 4; s++) {
      int j = jbase + s;
      const float* eyr = ey + j * 16;
      float P0 = 0.f, P1 = 0.f;
#pragma unroll
      for (int a = 0; a < 16; a++) {
        float w = eyr[a];
        P0 += w * ex0s[bl][a];
        P1 += w * ex1s[bl][a];
      }
      float2 ed = ED[j];
      float X10 = ed.x * P0 + ed.y * P1;       // exp(z0)
      float X11 = 2.0f * ed.x * P1;            // exp(z1): logaddexp(d0+y1, d0+y1)
      float2 xc = XC[j];
      float W0 = xc.x, W1 = xc.y;
      S1 += S2 * X10 * W1;
      S3 += S2 * X11 * W0;
      S2 *= (X10 * W0 + X11 * W1);
    }
    a_lds[bl][ng][0] = logf(S1 + S2);          // a1
    a_lds[bl][ng][1] = logf(S3);               // a2
  }
  __syncthreads();

  // phase 3: attn over 256 branches + final logsumexp against values
  float attn[8];
  float mx = -3.0e38f;
#pragma unroll
  for (int r = 0; r < 8; r++) {
    int k = chunk + 32 * r;
    float ssum = 0.f;
#pragma unroll
    for (int i2 = 0; i2 < 8; i2++) {
      int node = ((1 << i2) - 1) + (k & ((1 << i2) - 1));
      int ch   = (k >> i2) & 1;
      ssum += a_lds[bl][node][ch];
    }
    attn[r] = ssum;
    mx = fmaxf(mx, ssum);
  }
#pragma unroll
  for (int off = 1; off < 32; off <<= 1)
    mx = fmaxf(mx, __shfl_xor(mx, off, 64));
  mx = fmaxf(mx, -1.0e30f);                    // NaN guard if all -inf

  float acc[16];
#pragma unroll
  for (int q = 0; q < 16; q++) acc[q] = 0.f;
#pragma unroll
  for (int r = 0; r < 8; r++) {
    int k = chunk + 32 * r;
    float e = expf(attn[r] - mx);
#pragma unroll
    for (int d = 0; d < 8; d++) {
      acc[d]     += e * ev0s[d * 256 + k];
      acc[8 + d] += e * ev1s[d * 256 + k];
    }
  }
#pragma unroll
  for (int off = 1; off < 32; off <<= 1) {
#pragma unroll
    for (int q = 0; q < 16; q++)
      acc[q] += __shfl_xor(acc[q], off, 64);
  }

  int b = b0 + bl;
  if (chunk < 8)
    out[b * 8 + chunk] = mx + logf(acc[chunk]);                 // y0
  else if (chunk < 16)
    out[8192 * 8 + b * 8 + (chunk - 8)] = mx + logf(acc[chunk]); // y1
}

extern "C" void kernel_launch(void* const* d_in, const int* in_sizes, int n_in,
                              void* d_out, int out_size, void* d_ws, size_t ws_size,
                              hipStream_t stream) {
  WPtrs p;
  const float* x0 = (const float*)d_in[0];
  const float* x1 = (const float*)d_in[1];
  // setup_inputs() dict order is interleaved (sw0,dw0,cw0,sw1,...); the
  // reference signature is grouped. Detect via in_sizes[3]:
  //   interleaved -> dw0 has 8 elements; grouped -> sw1 has 64.
  if (in_sizes[3] == 8) {
    for (int i = 0; i < 8; i++) {
      p.sw[i] = (const float*)d_in[2 + 3 * i];
      p.dw[i] = (const float*)d_in[3 + 3 * i];
      p.cw[i] = (const float*)d_in[4 + 3 * i];
    }
  } else {
    for (int i = 0; i < 8; i++) {
      p.sw[i] = (const float*)d_in[2 + i];
      p.dw[i] = (const float*)d_in[10 + i];
      p.cw[i] = (const float*)d_in[18 + i];
    }
  }
  p.vw = (const float*)d_in[26];

  float* ws = (float*)d_ws;
  tm_precompute<<<13, 256, 0, stream>>>(p, ws);
  tm_main<<<1024, 256, 0, stream>>>(x0, x1, ws, (float*)d_out);
}

// Round 2
// 129.183 us; speedup vs baseline: 1.3175x; 1.3175x over previous
//
#include <hip/hip_runtime.h>
#include <math.h>

// ---------------------------------------------------------------------------
// Exp-domain tree machine, round 2: transposed coalesced float4 ey loads,
// 2 batch elements per wave, packed per-node float4 weights, fast
// __expf/__logf transcendentals.
// ---------------------------------------------------------------------------

// workspace layout (float offsets)
#define NWS_EYT  0        // ey_t[16][1020] : ey transposed [a][j]
#define NWS_EDXC 16320    // edxc[255][4][4]: per node,s: {ed0, ed1, c0, c1}
#define NWS_EVP  20400    // evp[256][16]   : per k: {ev0[0..7], ev1[0..7]}
// total 24496 floats = 97984 B

#define TINY 1.8600378e-44f   // exp(-BOUND - lc - LOG2)

struct WPtrs {
  const float* sw[8];
  const float* dw[8];
  const float* cw[8];
  const float* vw;
};

__device__ __forceinline__ float sigmoidf_(float x) {
  return 1.0f / (1.0f + __expf(-x));
}

__global__ void tm_precompute(WPtrs p, float* __restrict__ ws) {
  int tid = blockIdx.x * blockDim.x + threadIdx.x;
  if (tid < 1020) {
    int jg = tid;
    int v = (jg >> 2) + 1;
    int depth = 31 - __clz(v);
    int nS = (1 << depth) * 4;                 // rows (n*SHUF) at this depth
    int jl = jg - 4 * ((1 << depth) - 1);      // local row within depth
    const float* sw = p.sw[depth];             // (2, nS, 4)
    float p0[4];
#pragma unroll
    for (int k = 0; k < 4; k++)
      p0[k] = sigmoidf_(sw[jl * 4 + k] - sw[nS * 4 + jl * 4 + k]);
#pragma unroll
    for (int a = 0; a < 16; a++) {
      float prod = 1.0f;
#pragma unroll
      for (int k = 0; k < 4; k++) {
        int bit = (a >> (3 - k)) & 1;          // k=0 is MSB
        prod *= bit ? p0[k] : (1.0f - p0[k]);
      }
      ws[NWS_EYT + a * 1020 + jg] = prod;      // transposed [a][j]
    }
    const float* dw = p.dw[depth];             // (2, nS)
    float e0 = sigmoidf_(dw[jl] - dw[nS + jl]);
    const float* cw = p.cw[depth];             // (2, 1, n, 4) flat (2, nS)
    float c0 = sigmoidf_(cw[jl] - cw[nS + jl]);
    int ng = jg >> 2, s = jg & 3;
    float* q = ws + NWS_EDXC + ng * 16 + s * 4;
    q[0] = e0; q[1] = 1.0f - e0; q[2] = c0; q[3] = 1.0f - c0;
  } else if (tid >= 1024 && tid < 3072) {
    int e = tid - 1024;                        // e = k*8 + d
    int k = e >> 3, d = e & 7;
    float v0 = sigmoidf_(p.vw[e] - p.vw[2048 + e]);
    ws[NWS_EVP + k * 16 + d]     = v0;
    ws[NWS_EVP + k * 16 + 8 + d] = 1.0f - v0;
  }
}

// 8 batch elements per block of 256; each wave handles 2 batch elements,
// lane = node chunk (64-wide split of 255 nodes).
__global__ __launch_bounds__(256) void tm_main(
    const float* __restrict__ x0, const float* __restrict__ x1,
    const float* __restrict__ ws, float* __restrict__ out) {
  __shared__ float ex0s[8][16];
  __shared__ float ex1s[8][16];
  __shared__ float a_lds[8][255][2];           // per-node (a1, a2), log domain

  const int t  = threadIdx.x;
  const int b0 = blockIdx.x * 8;

  // stage exp(x) for this block's 8 batch rows
  {
    int bl = t >> 5, a = t & 31;
    if (a < 16) ex0s[bl][a]      = __expf(x0[(b0 + bl) * 16 + a]);
    else        ex1s[bl][a - 16] = __expf(x1[(b0 + bl) * 16 + (a - 16)]);
  }
  __syncthreads();

  const int wb   = t >> 6;        // wave id: handles batch rows 2wb, 2wb+1
  const int lane = t & 63;
  const int bl0  = wb * 2, bl1 = bl0 + 1;

  // hoist broadcast ex values into registers (reused across 4 node-iters)
  float e0A[16], e1A[16], e0B[16], e1B[16];
#pragma unroll
  for (int a = 0; a < 16; a++) {
    e0A[a] = ex0s[bl0][a]; e1A[a] = ex1s[bl0][a];
    e0B[a] = ex0s[bl1][a]; e1B[a] = ex1s[bl1][a];
  }

  const float*  __restrict__ eyt  = ws + NWS_EYT;
  const float4* __restrict__ edxc = (const float4*)(ws + NWS_EDXC);

  // phase 2: per-node compare_fwd recurrence in exp domain
#pragma unroll
  for (int r = 0; r < 4; r++) {
    int ng = lane + 64 * r;
    if (ng < 255) {
      float PA0[4] = {0,0,0,0}, PA1[4] = {0,0,0,0};
      float PB0[4] = {0,0,0,0}, PB1[4] = {0,0,0,0};
#pragma unroll
      for (int a = 0; a < 16; a++) {
        const float4 w = *(const float4*)(eyt + a * 1020 + (ng << 2));
        const float wa[4] = {w.x, w.y, w.z, w.w};
#pragma unroll
        for (int s = 0; s < 4; s++) {
          PA0[s] = fmaf(wa[s], e0A[a], PA0[s]);
          PA1[s] = fmaf(wa[s], e1A[a], PA1[s]);
          PB0[s] = fmaf(wa[s], e0B[a], PB0[s]);
          PB1[s] = fmaf(wa[s], e1B[a], PB1[s]);
        }
      }
      float S1a = TINY, S2a = 1.0f, S3a = TINY;
      float S1b = TINY, S2b = 1.0f, S3b = TINY;
#pragma unroll
      for (int s = 0; s < 4; s++) {
        const float4 q = edxc[(ng << 2) + s];  // {ed0, ed1, W0, W1}
        {
          float X10 = fmaf(q.x, PA0[s], q.y * PA1[s]);
          float T   = 2.0f * q.x * PA1[s];
          S1a = fmaf(S2a, X10 * q.w, S1a);
          S3a = fmaf(S2a, T * q.z, S3a);
          S2a *= fmaf(X10, q.z, T * q.w);
        }
        {
          float X10 = fmaf(q.x, PB0[s], q.y * PB1[s]);
          float T   = 2.0f * q.x * PB1[s];
          S1b = fmaf(S2b, X10 * q.w, S1b);
          S3b = fmaf(S2b, T * q.z, S3b);
          S2b *= fmaf(X10, q.z, T * q.w);
        }
      }
      a_lds[bl0][ng][0] = __logf(S1a + S2a);
      a_lds[bl0][ng][1] = __logf(S3a);
      a_lds[bl1][ng][0] = __logf(S1b + S2b);
      a_lds[bl1][ng][1] = __logf(S3b);
    }
  }
  __syncthreads();

  // phase 3: attn over 256 branches + final logsumexp against values
  const int bl    = t >> 5;
  const int chunk = t & 31;
  const float4* __restrict__ evp = (const float4*)(ws + NWS_EVP);

  float attn[8];
  float mx = -3.0e38f;
#pragma unroll
  for (int r = 0; r < 8; r++) {
    int k = chunk + 32 * r;
    float ssum = 0.f;
#pragma unroll
    for (int i2 = 0; i2 < 8; i2++) {
      int node = ((1 << i2) - 1) + (k & ((1 << i2) - 1));
      int ch   = (k >> i2) & 1;
      ssum += a_lds[bl][node][ch];
    }
    attn[r] = ssum;
    mx = fmaxf(mx, ssum);
  }
#pragma unroll
  for (int off = 1; off < 32; off <<= 1)
    mx = fmaxf(mx, __shfl_xor(mx, off, 64));
  mx = fmaxf(mx, -1.0e30f);                    // guard if all -inf

  float acc[16];
#pragma unroll
  for (int q = 0; q < 16; q++) acc[q] = 0.f;
#pragma unroll
  for (int r = 0; r < 8; r++) {
    int k = chunk + 32 * r;
    float e = __expf(attn[r] - mx);
    float4 v0 = evp[k * 4 + 0];
    float4 v1 = evp[k * 4 + 1];
    float4 v2 = evp[k * 4 + 2];
    float4 v3 = evp[k * 4 + 3];
    acc[0]  = fmaf(e, v0.x, acc[0]);  acc[1]  = fmaf(e, v0.y, acc[1]);
    acc[2]  = fmaf(e, v0.z, acc[2]);  acc[3]  = fmaf(e, v0.w, acc[3]);
    acc[4]  = fmaf(e, v1.x, acc[4]);  acc[5]  = fmaf(e, v1.y, acc[5]);
    acc[6]  = fmaf(e, v1.z, acc[6]);  acc[7]  = fmaf(e, v1.w, acc[7]);
    acc[8]  = fmaf(e, v2.x, acc[8]);  acc[9]  = fmaf(e, v2.y, acc[9]);
    acc[10] = fmaf(e, v2.z, acc[10]); acc[11] = fmaf(e, v2.w, acc[11]);
    acc[12] = fmaf(e, v3.x, acc[12]); acc[13] = fmaf(e, v3.y, acc[13]);
    acc[14] = fmaf(e, v3.z, acc[14]); acc[15] = fmaf(e, v3.w, acc[15]);
  }
#pragma unroll
  for (int off = 1; off < 32; off <<= 1) {
#pragma unroll
    for (int q = 0; q < 16; q++)
      acc[q] += __shfl_xor(acc[q], off, 64);
  }

  int b = b0 + bl;
  if (chunk < 8)
    out[b * 8 + chunk] = mx + __logf(acc[chunk]);                  // y0
  else if (chunk < 16)
    out[8192 * 8 + b * 8 + (chunk - 8)] = mx + __logf(acc[chunk]); // y1
}

extern "C" void kernel_launch(void* const* d_in, const int* in_sizes, int n_in,
                              void* d_out, int out_size, void* d_ws, size_t ws_size,
                              hipStream_t stream) {
  WPtrs p;
  const float* x0 = (const float*)d_in[0];
  const float* x1 = (const float*)d_in[1];
  if (in_sizes[3] == 8) {        // interleaved dict order sw0,dw0,cw0,sw1,...
    for (int i = 0; i < 8; i++) {
      p.sw[i] = (const float*)d_in[2 + 3 * i];
      p.dw[i] = (const float*)d_in[3 + 3 * i];
      p.cw[i] = (const float*)d_in[4 + 3 * i];
    }
  } else {                       // grouped signature order
    for (int i = 0; i < 8; i++) {
      p.sw[i] = (const float*)d_in[2 + i];
      p.dw[i] = (const float*)d_in[10 + i];
      p.cw[i] = (const float*)d_in[18 + i];
    }
  }
  p.vw = (const float*)d_in[26];

  float* ws = (float*)d_ws;
  tm_precompute<<<13, 256, 0, stream>>>(p, ws);
  tm_main<<<1024, 256, 0, stream>>>(x0, x1, ws, (float*)d_out);
}